// Round 1
// 648.956 us; speedup vs baseline: 1.0210x; 1.0210x over previous
//
#include <hip/hip_runtime.h>
#include <math.h>

#define BATCH 4
#define NTOK  16384
#define CDIM  512
#define NH    8
#define HD    64
#define M_ROWS (BATCH*NTOK)
#define KDIM  512

typedef _Float16 f16;
typedef _Float16 f16x8 __attribute__((ext_vector_type(8)));
typedef _Float16 f16x4 __attribute__((ext_vector_type(4)));
typedef _Float16 f16x2 __attribute__((ext_vector_type(2)));
typedef float    f32x4 __attribute__((ext_vector_type(4)));

__device__ __forceinline__ void load_lds16(const void* g, void* l) {
    __builtin_amdgcn_global_load_lds(
        (const __attribute__((address_space(1))) void*)g,
        (__attribute__((address_space(3))) void*)l, 16, 0, 0);
}

__global__ void rope_tables(float* __restrict__ tab) {
    int tid = threadIdx.x;
    for (int i = 0; i < 32; i++) {
        int idx = tid + i * 256;
        int grp = idx >> 11;
        int rem = idx & 2047;
        int t   = rem >> 4;
        int fi  = rem & 15;
        float freq_f = (float)pow(10.0, -(double)fi / 16.0);
        double ang = (double)t * (double)freq_f;
        tab[idx] = (float)((grp & 1) ? sin(ang) : cos(ang));
    }
}

__global__ void convert_x_f16(const float* __restrict__ in, f16* __restrict__ outp) {
    int i = blockIdx.x * 256 + threadIdx.x;
    float4 a = *(const float4*)&in[(size_t)i * 8];
    float4 b = *(const float4*)&in[(size_t)i * 8 + 4];
    f16x8 o;
    o[0]=(f16)a.x; o[1]=(f16)a.y; o[2]=(f16)a.z; o[3]=(f16)a.w;
    o[4]=(f16)b.x; o[5]=(f16)b.y; o[6]=(f16)b.z; o[7]=(f16)b.w;
    *(f16x8*)&outp[(size_t)i * 8] = o;
}

__global__ void convert_wT(const float* __restrict__ w, f16* __restrict__ wt, int N) {
    int idx = blockIdx.x * 256 + threadIdx.x;
    int n = idx >> 9, k = idx & 511;
    wt[idx] = (f16)w[(size_t)k * N + n];
}

// ---------------- fp16 MFMA GEMM, 128x128 tile, BK=64 per barrier ------------
// LDS tiles are [128][64] f16 (row stride 128B = one full bank wrap).
// T2 XOR-swizzle: physical 16B chunk = logical ^ (row&7). global_load_lds
// writes linearly (wave-uniform base + lane*16B), so the swizzle is applied by
// pre-swizzling the per-lane GLOBAL source chunk and applying the same XOR on
// the ds_read side (both-sides-or-neither, guide rule 21). Fragment reads:
// lanes 0..15 walk 16 consecutive rows at fixed logical chunk -> (r&7) covers
// all 8 slots twice -> 2 lanes/bank = conflict-free (m136: 2-way is free).
// XCD-swizzled 1D grid: xcd = bid&7, col-tile fastest within an XCD so one
// A row-tile + B stay resident in that XCD's 4MB L2.
template<int MODE>
__global__ __launch_bounds__(256, 2)
void gemm_f16(const f16* __restrict__ A, const f16* __restrict__ Bt,
              const float* __restrict__ bias,
              float* __restrict__ Co,
              f16* __restrict__ qd, f16* __restrict__ kd, f16* __restrict__ vd,
              const float* __restrict__ tab, int ncol_tiles)
{
    __shared__ f16 As[128 * 64];
    __shared__ f16 Bs[128 * 64];
    const int tid  = threadIdx.x;
    const int lane = tid & 63;
    const int wave = tid >> 6;
    const int wy = wave >> 1, wx = wave & 1;

    const int bid = blockIdx.x;
    const int xcd = bid & 7;
    const int idx = bid >> 3;
    const int ct  = idx % ncol_tiles;
    const int rt  = (idx / ncol_tiles) * 8 + xcd;
    const int row0 = rt * 128;
    const int col0 = ct * 128;

    const int l15 = lane & 15;
    const int l4  = lane >> 4;

    f32x4 acc[4][4];
    #pragma unroll
    for (int mt = 0; mt < 4; mt++)
        #pragma unroll
        for (int nt = 0; nt < 4; nt++)
            acc[mt][nt] = (f32x4){0.f, 0.f, 0.f, 0.f};

    const int pbase = wave * 256;   // 16B-chunk base for this wave (4 issues x 64)

    for (int k0 = 0; k0 < KDIM; k0 += 64) {
        #pragma unroll
        for (int i = 0; i < 4; i++) {
            int p  = pbase + i * 64 + lane;   // chunk id 0..1023
            int m  = p >> 3;                  // tile row 0..127
            int jp = p & 7;                   // physical 16B chunk within row
            int j  = jp ^ (m & 7);            // logical k-chunk to fetch (swizzle)
            load_lds16(&A [(size_t)(row0 + m) * KDIM + k0 + j * 8],
                       &As[(pbase + i * 64) * 8]);
            load_lds16(&Bt[(size_t)(col0 + m) * KDIM + k0 + j * 8],
                       &Bs[(pbase + i * 64) * 8]);
        }
        __syncthreads();

        #pragma unroll
        for (int s = 0; s < 2; s++) {
            f16x8 af[4], bf[4];
            #pragma unroll
            for (int t = 0; t < 4; t++) {
                int ra = wy * 64 + t * 16 + l15;
                int rb = wx * 64 + t * 16 + l15;
                int ca = ((s << 2) | l4) ^ (ra & 7);
                int cb = ((s << 2) | l4) ^ (rb & 7);
                af[t] = *(const f16x8*)&As[ra * 64 + ca * 8];
                bf[t] = *(const f16x8*)&Bs[rb * 64 + cb * 8];
            }
            #pragma unroll
            for (int mt = 0; mt < 4; mt++)
                #pragma unroll
                for (int nt = 0; nt < 4; nt++)
                    acc[mt][nt] = __builtin_amdgcn_mfma_f32_16x16x32_f16(af[mt], bf[nt], acc[mt][nt], 0, 0, 0);
        }
        __syncthreads();
    }

    if (MODE == 0) {
        // LDS-transpose epilogue: 4 steps of 32 rows x 128 cols fp32 (16 KB,
        // aliases As), flushed as fully-coalesced float4 stores.
        float* ep = (float*)&As[0];              // 32*128 floats
        #pragma unroll
        for (int mt = 0; mt < 4; mt++) {
            #pragma unroll
            for (int nt = 0; nt < 4; nt++) {
                int col = wx * 64 + nt * 16 + l15;
                float bv = bias[col0 + col];
                #pragma unroll
                for (int r = 0; r < 4; r++) {
                    int rp = wy * 16 + l4 * 4 + r;  // 0..31
                    ep[rp * 128 + col] = acc[mt][nt][r] + bv;
                }
            }
            __syncthreads();
            #pragma unroll
            for (int j = 0; j < 4; j++) {
                int id = tid + j * 256;             // 0..1023 float4s
                int rp = id >> 5, c4 = id & 31;
                int grow = row0 + (rp >> 4) * 64 + mt * 16 + (rp & 15);
                float4 v4 = *(const float4*)&ep[rp * 128 + c4 * 4];
                *(float4*)&Co[(size_t)grow * CDIM + col0 + c4 * 4] = v4;
            }
            __syncthreads();
        }
    } else {
        const int which = col0 >> 9;
        f16* dst = (which == 0) ? qd : (which == 1) ? kd : vd;
        #pragma unroll
        for (int nt = 0; nt < 4; nt++) {
            int coln = col0 + wx * 64 + nt * 16 + l15;
            int c512 = coln & 511;
            float bv = bias[coln];
            if (which == 2) {
                #pragma unroll
                for (int mt = 0; mt < 4; mt++)
                    #pragma unroll
                    for (int r = 0; r < 4; r++) {
                        int row = row0 + wy * 64 + mt * 16 + l4 * 4 + r;
                        float val = acc[mt][nt][r] + bv;
                        float pv  = __shfl_xor(val, 1, 64);
                        if (!(lane & 1)) {
                            f16x2 pk; pk[0] = (f16)val; pk[1] = (f16)pv;
                            *(f16x2*)&dst[(size_t)row * CDIM + c512] = pk;
                        }
                    }
            } else {
                int ch  = c512 & 63;
                int isy = ch >> 5;
                int fid = (ch & 31) >> 1;
                const float* ctb = tab + (isy ? 4096 : 0)    + fid;
                const float* stb = tab + (isy ? 6144 : 2048) + fid;
                #pragma unroll
                for (int mt = 0; mt < 4; mt++)
                    #pragma unroll
                    for (int r = 0; r < 4; r++) {
                        int row = row0 + wy * 64 + mt * 16 + l4 * 4 + r;
                        int tok = row & (NTOK - 1);
                        int t   = isy ? (tok >> 7) : (tok & 127);
                        float c = ctb[t * 16], s = stb[t * 16];
                        float val = acc[mt][nt][r] + bv;
                        float pv  = __shfl_xor(val, 1, 64);
                        float xr = (lane & 1) ? pv  : val;
                        float xi = (lane & 1) ? val : pv;
                        float o_r = xr * c - xi * s;
                        float o_i = xr * s + xi * c;
                        o_r = (o_r > 0.f) ? o_r + 1.f : __expf(o_r);
                        o_i = (o_i > 0.f) ? o_i + 1.f : __expf(o_i);
                        if (!(lane & 1)) {
                            f16x2 pk; pk[0] = (f16)o_r; pk[1] = (f16)o_i;
                            *(f16x2*)&dst[(size_t)row * CDIM + c512] = pk;
                        }
                    }
            }
        }
    }
}

__global__ __launch_bounds__(256, 4)
void kv_kernel(const f16* __restrict__ kk, const f16* __restrict__ vv,
               float* __restrict__ kv, float* __restrict__ ksum)
{
    int bh = blockIdx.x;
    int b = bh >> 3, h = bh & 7;
    int t0 = blockIdx.y * 1024;
    __shared__ float ks[64][68];
    __shared__ float vs[64][68];
    int tid = threadIdx.x;
    int tx = tid & 15;
    int ty = tid >> 4;
    float acc[4][4];
    float ksacc[4];
    #pragma unroll
    for (int r = 0; r < 4; r++) { ksacc[r] = 0.f;
        #pragma unroll
        for (int j = 0; j < 4; j++) acc[r][j] = 0.f; }

    const size_t rowbase = (size_t)b * NTOK;
    for (int tt = t0; tt < t0 + 1024; tt += 64) {
        #pragma unroll
        for (int i = 0; i < 2; i++) {
            int idx = tid + i * 256;
            int tok = idx >> 3;
            int o   = (idx & 7) * 8;
            size_t g = (rowbase + tt + tok) * CDIM + h * HD + o;
            f16x8 k8 = *(const f16x8*)&kk[g];
            f16x8 v8 = *(const f16x8*)&vv[g];
            float4 klo = {(float)k8[0], (float)k8[1], (float)k8[2], (float)k8[3]};
            float4 khi = {(float)k8[4], (float)k8[5], (float)k8[6], (float)k8[7]};
            float4 vlo = {(float)v8[0], (float)v8[1], (float)v8[2], (float)v8[3]};
            float4 vhi = {(float)v8[4], (float)v8[5], (float)v8[6], (float)v8[7]};
            *(float4*)&ks[tok][o]     = klo;
            *(float4*)&ks[tok][o + 4] = khi;
            *(float4*)&vs[tok][o]     = vlo;
            *(float4*)&vs[tok][o + 4] = vhi;
        }
        __syncthreads();
        #pragma unroll 8
        for (int t = 0; t < 64; t++) {
            float4 kd4 = *(const float4*)&ks[t][ty * 4];
            float4 vd4 = *(const float4*)&vs[t][tx * 4];
            float ka[4] = {kd4.x, kd4.y, kd4.z, kd4.w};
            float va[4] = {vd4.x, vd4.y, vd4.z, vd4.w};
            #pragma unroll
            for (int r = 0; r < 4; r++) {
                ksacc[r] += ka[r];
                #pragma unroll
                for (int j = 0; j < 4; j++) acc[r][j] += ka[r] * va[j];
            }
        }
        __syncthreads();
    }
    #pragma unroll
    for (int r = 0; r < 4; r++)
        #pragma unroll
        for (int j = 0; j < 4; j++)
            atomicAdd(&kv[bh * 4096 + (ty * 4 + r) * 64 + tx * 4 + j], acc[r][j]);
    if (tx == 0) {
        #pragma unroll
        for (int r = 0; r < 4; r++) atomicAdd(&ksum[bh * 64 + ty * 4 + r], ksacc[r]);
    }
}

__global__ __launch_bounds__(256, 4)
void attn_kernel(const f16* __restrict__ q, const float* __restrict__ kv,
                 const float* __restrict__ ksum, f16* __restrict__ attnh)
{
    int bh = blockIdx.x;
    int b = bh >> 3, h = bh & 7;
    int rc = blockIdx.y;
    __shared__ float kvs[64][68];
    __shared__ float qs[64][68];
    __shared__ float ksums[64];
    __shared__ float zpart[64][4];
    __shared__ float zs[64];
    int tid = threadIdx.x;
    int tx = tid & 15;
    int ty = tid >> 4;

    #pragma unroll
    for (int i = 0; i < 4; i++) {
        int idx = tid + i * 256;
        *(float4*)&kvs[idx >> 4][(idx & 15) * 4] = *(const float4*)&kv[bh * 4096 + idx * 4];
    }
    if (tid < 64) ksums[tid] = ksum[bh * 64 + tid];

    for (int sub = 0; sub < 4; sub++) {
        int r0 = rc * 256 + sub * 64;
        #pragma unroll
        for (int i = 0; i < 2; i++) {
            int idx = tid + i * 256;
            int rr = idx >> 3;
            int o  = (idx & 7) * 8;
            f16x8 q8 = *(const f16x8*)&q[((size_t)b * NTOK + r0 + rr) * CDIM + h * HD + o];
            float4 lo = {(float)q8[0], (float)q8[1], (float)q8[2], (float)q8[3]};
            float4 hi = {(float)q8[4], (float)q8[5], (float)q8[6], (float)q8[7]};
            *(float4*)&qs[rr][o]     = lo;
            *(float4*)&qs[rr][o + 4] = hi;
        }
        __syncthreads();
        {
            int row = tid & 63, g = tid >> 6;
            float p = 0.f;
            #pragma unroll
            for (int d = 0; d < 16; d++) p += qs[row][g * 16 + d] * ksums[g * 16 + d];
            zpart[row][g] = p;
        }
        __syncthreads();
        if (tid < 64)
            zs[tid] = 1.f / (zpart[tid][0] + zpart[tid][1] + zpart[tid][2] + zpart[tid][3] + 1e-6f);
        __syncthreads();

        float acc[4][4];
        #pragma unroll
        for (int r = 0; r < 4; r++)
            #pragma unroll
            for (int e = 0; e < 4; e++) acc[r][e] = 0.f;

        for (int d = 0; d < 64; d += 4) {
            float qa[4][4], ka[4][4];
            #pragma unroll
            for (int r = 0; r < 4; r++) {
                float4 v4 = *(const float4*)&qs[ty * 4 + r][d];
                qa[r][0]=v4.x; qa[r][1]=v4.y; qa[r][2]=v4.z; qa[r][3]=v4.w;
            }
            #pragma unroll
            for (int j = 0; j < 4; j++) {
                float4 v4 = *(const float4*)&kvs[d + j][tx * 4];
                ka[j][0]=v4.x; ka[j][1]=v4.y; ka[j][2]=v4.z; ka[j][3]=v4.w;
            }
            #pragma unroll
            for (int r = 0; r < 4; r++)
                #pragma unroll
                for (int j = 0; j < 4; j++)
                    #pragma unroll
                    for (int e = 0; e < 4; e++)
                        acc[r][e] += qa[r][j] * ka[j][e];
        }
        #pragma unroll
        for (int r = 0; r < 4; r++) {
            float z = zs[ty * 4 + r];
            f16x4 o4;
            o4[0] = (f16)(acc[r][0] * z); o4[1] = (f16)(acc[r][1] * z);
            o4[2] = (f16)(acc[r][2] * z); o4[3] = (f16)(acc[r][3] * z);
            *(f16x4*)&attnh[((size_t)b * NTOK + r0 + ty * 4 + r) * CDIM + h * HD + tx * 4] = o4;
        }
        __syncthreads();
    }
}

extern "C" void kernel_launch(void* const* d_in, const int* in_sizes, int n_in,
                              void* d_out, int out_size, void* d_ws, size_t ws_size,
                              hipStream_t stream)
{
    const float* x      = (const float*)d_in[0];
    const float* w_qkv  = (const float*)d_in[1];
    const float* b_qkv  = (const float*)d_in[2];
    const float* w_proj = (const float*)d_in[3];
    const float* b_proj = (const float*)d_in[4];
    float* out = (float*)d_out;
    char*  ws  = (char*)d_ws;

    const size_t NCB = (size_t)M_ROWS * CDIM * sizeof(f16);   // 64 MiB
    f16*   xh   = (f16*)(ws);
    f16*   qh   = (f16*)(ws + NCB * 1);
    f16*   kh   = (f16*)(ws + NCB * 2);
    f16*   vh   = (f16*)(ws + NCB * 3);          // reused as attn_h after kv_kernel
    f16*   wqt  = (f16*)(ws + NCB * 4);
    f16*   wpt  = (f16*)(ws + NCB * 4 + (1536 * 512) * sizeof(f16));
    float* tab  = (float*)(ws + NCB * 4 + (1536 * 512 + 512 * 512) * sizeof(f16));
    float* kvp  = tab + 8192;
    float* ksum = kvp + 32 * 4096;

    hipMemsetAsync(kvp, 0, (32 * 4096 + 32 * 64) * sizeof(float), stream);
    rope_tables<<<1, 256, 0, stream>>>(tab);
    convert_x_f16<<<M_ROWS * CDIM / 8 / 256, 256, 0, stream>>>(x, xh);
    convert_wT<<<1536 * 512 / 256, 256, 0, stream>>>(w_qkv, wqt, 1536);
    convert_wT<<<512 * 512 / 256, 256, 0, stream>>>(w_proj, wpt, 512);

    gemm_f16<1><<<6144, 256, 0, stream>>>(xh, wqt, b_qkv,
                                          nullptr, qh, kh, vh, tab, 12);
    kv_kernel<<<dim3(32, 16), 256, 0, stream>>>(kh, vh, kvp, ksum);
    attn_kernel<<<dim3(32, 64), 256, 0, stream>>>(qh, kvp, ksum, vh);
    gemm_f16<0><<<2048, 256, 0, stream>>>(vh, wpt, b_proj,
                                          out, nullptr, nullptr, nullptr, nullptr, 4);
}